// Round 4
// baseline (435.638 us; speedup 1.0000x reference)
//
#include <hip/hip_runtime.h>
#include <hip/hip_bf16.h>
#include <math.h>

typedef __attribute__((ext_vector_type(8))) short bf16x8;
typedef __attribute__((ext_vector_type(4))) short s16x4;
typedef __attribute__((ext_vector_type(4))) float f32x4;

static __device__ __forceinline__ short f2bf(float f) {
    union { float f; unsigned u; } v; v.f = f;
    unsigned r = v.u + 0x7FFFu + ((v.u >> 16) & 1u);
    return (short)(r >> 16);
}

// async global->LDS, 16B per lane; dest must be linear (base + lane*16)
#define GL2LDS16(g, s) __builtin_amdgcn_global_load_lds( \
    (const __attribute__((address_space(1))) void*)(g),  \
    (__attribute__((address_space(3))) void*)(s), 16, 0, 0)

// ---------------------------------------------------------------------------
// Weight transpose + fp32->bf16:  WT[n][k] = bf16(W[k][n]),  512x512 each
// ---------------------------------------------------------------------------
__global__ __launch_bounds__(256) void wt_kernel(
    const float* __restrict__ Wq, const float* __restrict__ Wk,
    const float* __restrict__ Wv, const float* __restrict__ Wo,
    short* __restrict__ WqT, short* __restrict__ WkT,
    short* __restrict__ WvT, short* __restrict__ WoT)
{
    __shared__ short lds[64][65];
    const float* src; short* dst;
    if (blockIdx.z == 0)      { src = Wq; dst = WqT; }
    else if (blockIdx.z == 1) { src = Wk; dst = WkT; }
    else if (blockIdx.z == 2) { src = Wv; dst = WvT; }
    else                      { src = Wo; dst = WoT; }
    const int kb = blockIdx.x * 64, nb = blockIdx.y * 64;
    const int t = threadIdx.x;
    const int c = t & 63, r0 = t >> 6;
#pragma unroll
    for (int rr = 0; rr < 16; ++rr) {
        const int r = r0 * 16 + rr;
        lds[c][r] = f2bf(src[(size_t)(kb + r) * 512 + nb + c]);
    }
    __syncthreads();
#pragma unroll
    for (int rr = 0; rr < 16; ++rr) {
        const int n = r0 * 16 + rr;
        dst[(size_t)(nb + n) * 512 + kb + c] = lds[n][c];
    }
}

// ---------------------------------------------------------------------------
// Memory slots: Kb rows 1024..1063 = sqrt(64)*memK; VbT cols 1024..1063
// Kb: [b*8+h][1064][64] bf16; VbT: [b*8+h][64][1088] bf16
// ---------------------------------------------------------------------------
__global__ __launch_bounds__(256) void mem_kernel(
    const float* __restrict__ memK, const float* __restrict__ memV,
    short* __restrict__ Kb, short* __restrict__ VbT)
{
    const int idx = blockIdx.x * 256 + threadIdx.x;
    if (idx >= 16 * 8 * 40 * 64) return;
    const int d = idx & 63;
    const int m = (idx >> 6) % 40;
    const int h = (idx / 2560) & 7;
    const int b = idx / 20480;
    const int src = m * 512 + h * 64 + d;
    const int bh = b * 8 + h;
    Kb[((size_t)bh * 1064 + 1024 + m) * 64 + d] = f2bf(8.0f * memK[src]);
    VbT[((size_t)bh * 64 + d) * 1088 + 1024 + m] = f2bf(sqrtf(40.0f) * memV[src]);
}

// ---------------------------------------------------------------------------
// Projection GEMM v2: A(fp32 [16384][512]) @ BT^T + bias -> bf16
// BM=64 BN=128 BK=64, global_load_lds staging, XOR-swizzled LDS.
// vmode==0: out[b,h,n,d] (OUTROWS rows); vmode==1: out[(b,h,d)][1088]+n
// ---------------------------------------------------------------------------
__global__ __launch_bounds__(256) void proj_gemm(
    const float* __restrict__ A, const short* __restrict__ BT,
    const float* __restrict__ bias, short* __restrict__ out, int OUTROWS, int vmode)
{
    __shared__ float As[4096];   // 64 rows x 256B (fp32), swizzled
    __shared__ short Bs[8192];   // 128 rows x 128B (bf16), swizzled
    const int t = threadIdx.x;
    const int lane = t & 63, w = t >> 6;
    const int wr = w >> 1, wc = w & 1;
    const int l16 = lane & 15, g4 = lane >> 4;
    const int m0 = blockIdx.y * 64, n0 = blockIdx.x * 128;

    f32x4 acc[2][4];
#pragma unroll
    for (int i = 0; i < 2; ++i)
#pragma unroll
        for (int j = 0; j < 4; ++j) acc[i][j] = (f32x4){0.f, 0.f, 0.f, 0.f};

    // staging address precompute (inverse-swizzled global sources)
    int arow_[4], acol_[4], brow_[4], bcol_[4];
#pragma unroll
    for (int c = 0; c < 4; ++c) {
        const int chunk = c * 4 + w;
        const int ar = chunk * 4 + (lane >> 4);
        const int alb = ((lane & 15) * 16) ^ ((ar & 7) << 4);
        arow_[c] = ar; acol_[c] = alb >> 2;            // float index in row
        const int br = chunk * 8 + (lane >> 3);
        const int blb = ((lane & 7) * 16) ^ ((br & 7) << 4);
        brow_[c] = br; bcol_[c] = blb >> 1;            // short index in row
    }

    for (int kt = 0; kt < 8; ++kt) {
        const int k0 = kt * 64;
#pragma unroll
        for (int c = 0; c < 4; ++c) {
            GL2LDS16(&A[(size_t)(m0 + arow_[c]) * 512 + k0 + acol_[c]],
                     &As[(c * 4 + w) * 256 + lane * 4]);
            GL2LDS16(&BT[(size_t)(n0 + brow_[c]) * 512 + k0 + bcol_[c]],
                     &Bs[(c * 4 + w) * 512 + lane * 8]);
        }
        __syncthreads();
#pragma unroll
        for (int kk = 0; kk < 2; ++kk) {
            bf16x8 af[2], bfr[4];
#pragma unroll
            for (int mi = 0; mi < 2; ++mi) {
                const int ar = wr * 32 + mi * 16 + l16;
                const int lb0 = (kk * 128 + g4 * 32) ^ ((ar & 7) << 4);
                const float4 f0 = *reinterpret_cast<const float4*>(
                    reinterpret_cast<const char*>(As) + ar * 256 + lb0);
                const float4 f1 = *reinterpret_cast<const float4*>(
                    reinterpret_cast<const char*>(As) + ar * 256 + (lb0 ^ 16));
                bf16x8 a;
                a[0] = f2bf(f0.x); a[1] = f2bf(f0.y); a[2] = f2bf(f0.z); a[3] = f2bf(f0.w);
                a[4] = f2bf(f1.x); a[5] = f2bf(f1.y); a[6] = f2bf(f1.z); a[7] = f2bf(f1.w);
                af[mi] = a;
            }
#pragma unroll
            for (int ni = 0; ni < 4; ++ni) {
                const int br = wc * 64 + ni * 16 + l16;
                const int lb = (kk * 64 + g4 * 16) ^ ((br & 7) << 4);
                bfr[ni] = *reinterpret_cast<const bf16x8*>(
                    reinterpret_cast<const char*>(Bs) + br * 128 + lb);
            }
#pragma unroll
            for (int mi = 0; mi < 2; ++mi)
#pragma unroll
                for (int ni = 0; ni < 4; ++ni)
                    acc[mi][ni] = __builtin_amdgcn_mfma_f32_16x16x32_bf16(af[mi], bfr[ni], acc[mi][ni], 0, 0, 0);
        }
        __syncthreads();
    }
#pragma unroll
    for (int mi = 0; mi < 2; ++mi) {
#pragma unroll
        for (int ni = 0; ni < 4; ++ni) {
            const int col = n0 + wc * 64 + ni * 16 + l16;
            const int h = col >> 6, d = col & 63;
            const float bb = bias[col];
#pragma unroll
            for (int r = 0; r < 4; ++r) {
                const int rowg = m0 + wr * 32 + mi * 16 + g4 * 4 + r;
                const int b = rowg >> 10, nn = rowg & 1023;
                const short val = f2bf(acc[mi][ni][r] + bb);
                if (vmode)
                    out[(((size_t)b * 8 + h) * 64 + d) * 1088 + nn] = val;
                else
                    out[(((size_t)b * 8 + h) * OUTROWS + nn) * 64 + d] = val;
            }
        }
    }
}

// ---------------------------------------------------------------------------
// Flash attention: 2048 blocks (XCD-swizzled), 4 waves, 64 q-rows/block.
// KVBLK=64, 17 tiles.  aw modulates k<1024; mask k>=1064.  Defer-max (THR=8).
// ---------------------------------------------------------------------------
__global__ __launch_bounds__(256) void attn_kernel(
    const short* __restrict__ Qb, const short* __restrict__ Kb,
    const short* __restrict__ VbT, const float* __restrict__ aw,
    short* __restrict__ AO)
{
    __shared__ short Ks[64][72];
    __shared__ short Vs[64][72];       // [dv][k]
    __shared__ short Ps[4][16][72];    // wave-private P tiles [q][k]

    const int n = blockIdx.x;
    const int xcd = n & 7, s_ = n >> 3, j = s_ & 7, gh = s_ >> 3;
    const int g = gh * 8 + xcd;        // 0..255 = b*16+qt
    const int h = j, qt = g & 15, b = g >> 4;
    const int bh = b * 8 + h;
    const int t = threadIdx.x;
    const int lane = t & 63, w = t >> 6;
    const int l16 = lane & 15, g4 = lane >> 4;
    const int qrow0 = qt * 64 + w * 16;

    bf16x8 qf0, qf1;
    {
        const short* qp = Qb + ((size_t)bh * 1024 + qrow0 + l16) * 64 + g4 * 8;
        qf0 = *reinterpret_cast<const bf16x8*>(qp);
        qf1 = *reinterpret_cast<const bf16x8*>(qp + 32);
    }

    f32x4 O[4];
#pragma unroll
    for (int i = 0; i < 4; ++i) O[i] = (f32x4){0.f, 0.f, 0.f, 0.f};
    float m_r[4] = {-1e30f, -1e30f, -1e30f, -1e30f};
    float l_r[4] = {0.f, 0.f, 0.f, 0.f};

    const int str = t >> 2;            // staging row 0..63
    const int stc = (t & 3) * 16;      // 0,16,32,48 (shorts)

    for (int kt = 0; kt < 17; ++kt) {
        const int kb = kt * 64;
        const bool useaw = (kb < 1024);
        float awv[4][4];
        if (useaw) {
#pragma unroll
            for (int r = 0; r < 4; ++r) {
                const size_t awbase = ((size_t)b * 1024 + qrow0 + g4 * 4 + r) * 1024 + kb + l16;
#pragma unroll
                for (int sub = 0; sub < 4; ++sub)
                    awv[r][sub] = aw[awbase + sub * 16];
            }
        }
        {   // stage K tile [64][64]
            const int rg = kb + str;
            bf16x8 k0 = {0,0,0,0,0,0,0,0}, k1 = {0,0,0,0,0,0,0,0};
            if (rg < 1064) {
                const short* kp = &Kb[((size_t)bh * 1064 + rg) * 64 + stc];
                k0 = *reinterpret_cast<const bf16x8*>(kp);
                k1 = *reinterpret_cast<const bf16x8*>(kp + 8);
            }
            *reinterpret_cast<bf16x8*>(&Ks[str][stc]) = k0;
            *reinterpret_cast<bf16x8*>(&Ks[str][stc + 8]) = k1;
        }
        {   // stage V^T tile [64 dv][64 k] from VbT (vectorized)
            const short* vp = &VbT[((size_t)bh * 64 + str) * 1088 + kb + stc];
            bf16x8 v0 = {0,0,0,0,0,0,0,0}, v1 = {0,0,0,0,0,0,0,0};
            if (kb + stc + 8 <= 1064)  v0 = *reinterpret_cast<const bf16x8*>(vp);
            if (kb + stc + 16 <= 1064) v1 = *reinterpret_cast<const bf16x8*>(vp + 8);
            *reinterpret_cast<bf16x8*>(&Vs[str][stc]) = v0;
            *reinterpret_cast<bf16x8*>(&Vs[str][stc + 8]) = v1;
        }
        __syncthreads();

        // QK^T: S[sub] covers k = kb+sub*16+l16, q rows qrow0+g4*4+r
        f32x4 S[4];
        __builtin_amdgcn_s_setprio(1);
#pragma unroll
        for (int sub = 0; sub < 4; ++sub) {
            bf16x8 kf0 = *reinterpret_cast<const bf16x8*>(&Ks[sub * 16 + l16][g4 * 8]);
            bf16x8 kf1 = *reinterpret_cast<const bf16x8*>(&Ks[sub * 16 + l16][32 + g4 * 8]);
            f32x4 z = {0.f, 0.f, 0.f, 0.f};
            z = __builtin_amdgcn_mfma_f32_16x16x32_bf16(qf0, kf0, z, 0, 0, 0);
            S[sub] = __builtin_amdgcn_mfma_f32_16x16x32_bf16(qf1, kf1, z, 0, 0, 0);
        }
        __builtin_amdgcn_s_setprio(0);

        const bool tail = (kb + 64 > 1064);
        float sv[4][4], mx[4];
#pragma unroll
        for (int r = 0; r < 4; ++r) {
#pragma unroll
            for (int sub = 0; sub < 4; ++sub) {
                float x = S[sub][r] * 0.125f;
                if (useaw) x *= awv[r][sub];
                if (tail && (kb + sub * 16 + l16 >= 1064)) x = -1e30f;
                sv[r][sub] = x;
            }
            float m2 = fmaxf(fmaxf(sv[r][0], sv[r][1]), fmaxf(sv[r][2], sv[r][3]));
#pragma unroll
            for (int off = 1; off < 16; off <<= 1)
                m2 = fmaxf(m2, __shfl_xor(m2, off));
            mx[r] = m2;
        }
        // defer-max: only rescale when some row grew past threshold
        bool grew = false;
#pragma unroll
        for (int r = 0; r < 4; ++r) grew = grew || (mx[r] > m_r[r] + 8.0f);
        if (__any(grew)) {
#pragma unroll
            for (int r = 0; r < 4; ++r) {
                const float mn = fmaxf(m_r[r], mx[r]);
                const float corr = __expf(m_r[r] - mn);
                m_r[r] = mn;
                l_r[r] *= corr;
#pragma unroll
                for (int i = 0; i < 4; ++i) O[i][r] *= corr;
            }
        }
#pragma unroll
        for (int r = 0; r < 4; ++r) {
            float rs = 0.f;
#pragma unroll
            for (int sub = 0; sub < 4; ++sub) {
                const float p = __expf(sv[r][sub] - m_r[r]);
                rs += p;
                Ps[w][g4 * 4 + r][sub * 16 + l16] = f2bf(p);
            }
#pragma unroll
            for (int off = 1; off < 16; off <<= 1)
                rs += __shfl_xor(rs, off);
            l_r[r] += rs;
        }
        // PV
        bf16x8 pf0 = *reinterpret_cast<const bf16x8*>(&Ps[w][l16][g4 * 8]);
        bf16x8 pf1 = *reinterpret_cast<const bf16x8*>(&Ps[w][l16][32 + g4 * 8]);
        __builtin_amdgcn_s_setprio(1);
#pragma unroll
        for (int sub = 0; sub < 4; ++sub) {
            bf16x8 vf0 = *reinterpret_cast<const bf16x8*>(&Vs[sub * 16 + l16][g4 * 8]);
            bf16x8 vf1 = *reinterpret_cast<const bf16x8*>(&Vs[sub * 16 + l16][32 + g4 * 8]);
            O[sub] = __builtin_amdgcn_mfma_f32_16x16x32_bf16(pf0, vf0, O[sub], 0, 0, 0);
            O[sub] = __builtin_amdgcn_mfma_f32_16x16x32_bf16(pf1, vf1, O[sub], 0, 0, 0);
        }
        __builtin_amdgcn_s_setprio(0);
        __syncthreads();
    }
    // epilogue: normalize and store AO[b*1024+q][h*64+dv] bf16
#pragma unroll
    for (int r = 0; r < 4; ++r) {
        const float inv = 1.0f / l_r[r];
        const int qg = qrow0 + g4 * 4 + r;
        const size_t base = ((size_t)b * 1024 + qg) * 512 + h * 64;
#pragma unroll
        for (int sub = 0; sub < 4; ++sub)
            AO[base + sub * 16 + l16] = f2bf(O[sub][r] * inv);
    }
}

// ---------------------------------------------------------------------------
// Output GEMM v2 + bias + residual: out(fp32) = AO(bf16) @ WoT^T + bo + queries
// BM=64 BN=128 BK=64, global_load_lds staging, XOR-swizzled LDS.
// ---------------------------------------------------------------------------
__global__ __launch_bounds__(256) void out_gemm(
    const short* __restrict__ A, const short* __restrict__ BT,
    const float* __restrict__ bias, const float* __restrict__ resid,
    float* __restrict__ out)
{
    __shared__ short Asb[4096];  // 64 rows x 128B bf16, swizzled
    __shared__ short Bs[8192];   // 128 rows x 128B bf16, swizzled
    const int t = threadIdx.x;
    const int lane = t & 63, w = t >> 6;
    const int wr = w >> 1, wc = w & 1;
    const int l16 = lane & 15, g4 = lane >> 4;
    const int m0 = blockIdx.y * 64, n0 = blockIdx.x * 128;

    f32x4 acc[2][4];
#pragma unroll
    for (int i = 0; i < 2; ++i)
#pragma unroll
        for (int j = 0; j < 4; ++j) acc[i][j] = (f32x4){0.f, 0.f, 0.f, 0.f};

    int arow_[2], acol_[2], brow_[4], bcol_[4];
#pragma unroll
    for (int c = 0; c < 2; ++c) {
        const int chunk = c * 4 + w;
        const int ar = chunk * 8 + (lane >> 3);
        const int alb = ((lane & 7) * 16) ^ ((ar & 7) << 4);
        arow_[c] = ar; acol_[c] = alb >> 1;
    }
#pragma unroll
    for (int c = 0; c < 4; ++c) {
        const int chunk = c * 4 + w;
        const int br = chunk * 8 + (lane >> 3);
        const int blb = ((lane & 7) * 16) ^ ((br & 7) << 4);
        brow_[c] = br; bcol_[c] = blb >> 1;
    }

    for (int kt = 0; kt < 8; ++kt) {
        const int k0 = kt * 64;
#pragma unroll
        for (int c = 0; c < 2; ++c)
            GL2LDS16(&A[(size_t)(m0 + arow_[c]) * 512 + k0 + acol_[c]],
                     &Asb[(c * 4 + w) * 512 + lane * 8]);
#pragma unroll
        for (int c = 0; c < 4; ++c)
            GL2LDS16(&BT[(size_t)(n0 + brow_[c]) * 512 + k0 + bcol_[c]],
                     &Bs[(c * 4 + w) * 512 + lane * 8]);
        __syncthreads();
#pragma unroll
        for (int kk = 0; kk < 2; ++kk) {
            bf16x8 af[2], bfr[4];
#pragma unroll
            for (int mi = 0; mi < 2; ++mi) {
                const int ar = wr * 32 + mi * 16 + l16;
                const int lb = (kk * 64 + g4 * 16) ^ ((ar & 7) << 4);
                af[mi] = *reinterpret_cast<const bf16x8*>(
                    reinterpret_cast<const char*>(Asb) + ar * 128 + lb);
            }
#pragma unroll
            for (int ni = 0; ni < 4; ++ni) {
                const int br = wc * 64 + ni * 16 + l16;
                const int lb = (kk * 64 + g4 * 16) ^ ((br & 7) << 4);
                bfr[ni] = *reinterpret_cast<const bf16x8*>(
                    reinterpret_cast<const char*>(Bs) + br * 128 + lb);
            }
#pragma unroll
            for (int mi = 0; mi < 2; ++mi)
#pragma unroll
                for (int ni = 0; ni < 4; ++ni)
                    acc[mi][ni] = __builtin_amdgcn_mfma_f32_16x16x32_bf16(af[mi], bfr[ni], acc[mi][ni], 0, 0, 0);
        }
        __syncthreads();
    }
#pragma unroll
    for (int mi = 0; mi < 2; ++mi) {
#pragma unroll
        for (int ni = 0; ni < 4; ++ni) {
            const int col = n0 + wc * 64 + ni * 16 + l16;
            const float bb = bias[col];
#pragma unroll
            for (int r = 0; r < 4; ++r) {
                const int rowg = m0 + wr * 32 + mi * 16 + g4 * 4 + r;
                out[(size_t)rowg * 512 + col] = acc[mi][ni][r] + bb + resid[(size_t)rowg * 512 + col];
            }
        }
    }
}

// ---------------------------------------------------------------------------
// LayerNorm in-place on d_out, one wave per 512-col row
// ---------------------------------------------------------------------------
__global__ __launch_bounds__(256) void ln_kernel(
    float* __restrict__ x, const float* __restrict__ gamma, const float* __restrict__ beta)
{
    const int row = blockIdx.x * 4 + (threadIdx.x >> 6);
    const int lane = threadIdx.x & 63;
    float* rp = x + (size_t)row * 512;
    const float4 v0 = *reinterpret_cast<const float4*>(&rp[lane * 4]);
    const float4 v1 = *reinterpret_cast<const float4*>(&rp[256 + lane * 4]);
    float s = v0.x + v0.y + v0.z + v0.w + v1.x + v1.y + v1.z + v1.w;
    float sq = v0.x * v0.x + v0.y * v0.y + v0.z * v0.z + v0.w * v0.w
             + v1.x * v1.x + v1.y * v1.y + v1.z * v1.z + v1.w * v1.w;
#pragma unroll
    for (int off = 1; off < 64; off <<= 1) {
        s += __shfl_xor(s, off);
        sq += __shfl_xor(sq, off);
    }
    const float mu = s * (1.f / 512.f);
    const float var = sq * (1.f / 512.f) - mu * mu;
    const float inv = rsqrtf(var + 1e-3f);
    const float4 g0 = *reinterpret_cast<const float4*>(&gamma[lane * 4]);
    const float4 g1 = *reinterpret_cast<const float4*>(&gamma[256 + lane * 4]);
    const float4 b0 = *reinterpret_cast<const float4*>(&beta[lane * 4]);
    const float4 b1 = *reinterpret_cast<const float4*>(&beta[256 + lane * 4]);
    float4 o0, o1;
    o0.x = (v0.x - mu) * inv * g0.x + b0.x;
    o0.y = (v0.y - mu) * inv * g0.y + b0.y;
    o0.z = (v0.z - mu) * inv * g0.z + b0.z;
    o0.w = (v0.w - mu) * inv * g0.w + b0.w;
    o1.x = (v1.x - mu) * inv * g1.x + b1.x;
    o1.y = (v1.y - mu) * inv * g1.y + b1.y;
    o1.z = (v1.z - mu) * inv * g1.z + b1.z;
    o1.w = (v1.w - mu) * inv * g1.w + b1.w;
    *reinterpret_cast<float4*>(&rp[lane * 4]) = o0;
    *reinterpret_cast<float4*>(&rp[256 + lane * 4]) = o1;
}

// ---------------------------------------------------------------------------
extern "C" void kernel_launch(void* const* d_in, const int* in_sizes, int n_in,
                              void* d_out, int out_size, void* d_ws, size_t ws_size,
                              hipStream_t stream) {
    const float* queries = (const float*)d_in[0];
    const float* keys    = (const float*)d_in[1];
    const float* values  = (const float*)d_in[2];
    const float* aw      = (const float*)d_in[3];
    const float* Wq = (const float*)d_in[4];
    const float* bq = (const float*)d_in[5];
    const float* Wk = (const float*)d_in[6];
    const float* bk = (const float*)d_in[7];
    const float* Wv = (const float*)d_in[8];
    const float* bv = (const float*)d_in[9];
    const float* Wo = (const float*)d_in[10];
    const float* bo = (const float*)d_in[11];
    const float* memK = (const float*)d_in[12];
    const float* memV = (const float*)d_in[13];
    const float* gamma = (const float*)d_in[14];
    const float* beta  = (const float*)d_in[15];
    float* out = (float*)d_out;

    char* ws = (char*)d_ws;
    short* WqT = (short*)(ws + 0);
    short* WkT = (short*)(ws + 524288);
    short* WvT = (short*)(ws + 1048576);
    short* WoT = (short*)(ws + 1572864);
    short* Qb  = (short*)(ws + 2097152);                       // 16.78 MB
    short* Kb  = (short*)(ws + 2097152 + 16777216);            // 17.43 MB
    short* VbT = (short*)(ws + 2097152 + 16777216 + 17432576); // 17.83 MB
    short* AO  = (short*)(ws + 2097152 + 16777216 + 17432576 + 17825792);

    wt_kernel<<<dim3(8, 8, 4), 256, 0, stream>>>(Wq, Wk, Wv, Wo, WqT, WkT, WvT, WoT);
    mem_kernel<<<dim3(1280), 256, 0, stream>>>(memK, memV, Kb, VbT);
    proj_gemm<<<dim3(4, 256), 256, 0, stream>>>(queries, WqT, bq, Qb, 1024, 0);
    proj_gemm<<<dim3(4, 256), 256, 0, stream>>>(keys, WkT, bk, Kb, 1064, 0);
    proj_gemm<<<dim3(4, 256), 256, 0, stream>>>(values, WvT, bv, VbT, 1064, 1);
    attn_kernel<<<dim3(2048), 256, 0, stream>>>(Qb, Kb, VbT, aw, AO);
    out_gemm<<<dim3(4, 256), 256, 0, stream>>>(AO, WoT, bo, queries, out);
    ln_kernel<<<dim3(4096), 256, 0, stream>>>(out, gamma, beta);
}

// Round 6
// 392.491 us; speedup vs baseline: 1.1099x; 1.1099x over previous
//
#include <hip/hip_runtime.h>
#include <hip/hip_bf16.h>
#include <math.h>

typedef __attribute__((ext_vector_type(8))) short bf16x8;
typedef __attribute__((ext_vector_type(4))) short s16x4;
typedef __attribute__((ext_vector_type(4))) float f32x4;

static __device__ __forceinline__ short f2bf(float f) {
    union { float f; unsigned u; } v; v.f = f;
    unsigned r = v.u + 0x7FFFu + ((v.u >> 16) & 1u);
    return (short)(r >> 16);
}

// async global->LDS, 16B per lane; dest must be linear (base + lane*16)
#define GL2LDS16(g, s) __builtin_amdgcn_global_load_lds( \
    (const __attribute__((address_space(1))) void*)(g),  \
    (__attribute__((address_space(3))) void*)(s), 16, 0, 0)

// ---------------------------------------------------------------------------
// Weight transpose + fp32->bf16:  WT[n][k] = bf16(W[k][n]),  512x512 each
// ---------------------------------------------------------------------------
__global__ __launch_bounds__(256) void wt_kernel(
    const float* __restrict__ Wq, const float* __restrict__ Wk,
    const float* __restrict__ Wv, const float* __restrict__ Wo,
    short* __restrict__ WqT, short* __restrict__ WkT,
    short* __restrict__ WvT, short* __restrict__ WoT)
{
    __shared__ short lds[64][65];
    const float* src; short* dst;
    if (blockIdx.z == 0)      { src = Wq; dst = WqT; }
    else if (blockIdx.z == 1) { src = Wk; dst = WkT; }
    else if (blockIdx.z == 2) { src = Wv; dst = WvT; }
    else                      { src = Wo; dst = WoT; }
    const int kb = blockIdx.x * 64, nb = blockIdx.y * 64;
    const int t = threadIdx.x;
    const int c = t & 63, r0 = t >> 6;
#pragma unroll
    for (int rr = 0; rr < 16; ++rr) {
        const int r = r0 * 16 + rr;
        lds[c][r] = f2bf(src[(size_t)(kb + r) * 512 + nb + c]);
    }
    __syncthreads();
#pragma unroll
    for (int rr = 0; rr < 16; ++rr) {
        const int n = r0 * 16 + rr;
        dst[(size_t)(nb + n) * 512 + kb + c] = lds[n][c];
    }
}

// ---------------------------------------------------------------------------
// Memory slots: Kb rows 1024..1063 = sqrt(64)*memK; VbT cols 1024..1063
// Kb: [b*8+h][1064][64] bf16; VbT: [b*8+h][64][1088] bf16
// ---------------------------------------------------------------------------
__global__ __launch_bounds__(256) void mem_kernel(
    const float* __restrict__ memK, const float* __restrict__ memV,
    short* __restrict__ Kb, short* __restrict__ VbT)
{
    const int idx = blockIdx.x * 256 + threadIdx.x;
    if (idx >= 16 * 8 * 40 * 64) return;
    // Kb path: d-fastest (coalesced dst)
    {
        const int d = idx & 63;
        const int m = (idx >> 6) % 40;
        const int h = (idx / 2560) & 7;
        const int b = idx / 20480;
        Kb[(((size_t)(b * 8 + h)) * 1064 + 1024 + m) * 64 + d] =
            f2bf(8.0f * memK[m * 512 + h * 64 + d]);
    }
    // VbT path: m-fastest (coalesced dst, 80B runs)
    {
        const int m = idx % 40;
        const int d = (idx / 40) & 63;
        const int h = (idx / 2560) & 7;
        const int b = idx / 20480;
        VbT[(((size_t)(b * 8 + h)) * 64 + d) * 1088 + 1024 + m] =
            f2bf(sqrtf(40.0f) * memV[m * 512 + h * 64 + d]);
    }
}

// ---------------------------------------------------------------------------
// Fused projection GEMM v3 (Q,K,V in one dispatch via blockIdx.y):
//   out = A(fp32 [16384][512]) @ BT^T + bias -> bf16
// BM=128 BN=128 BK=64, 4 waves x (64x64), global_load_lds staging,
// chunk-XOR swizzle (linear LDS dest + inverse-swizzled global source).
// XCD-grouped grid: the 4 n-tiles of one m-panel run back-to-back per XCD.
// ---------------------------------------------------------------------------
__global__ __launch_bounds__(256) void proj_gemm(
    const float* __restrict__ Aq, const float* __restrict__ Ak, const float* __restrict__ Av,
    const short* __restrict__ WqT, const short* __restrict__ WkT, const short* __restrict__ WvT,
    const float* __restrict__ bq, const float* __restrict__ bk, const float* __restrict__ bv,
    short* __restrict__ Qb, short* __restrict__ Kb, short* __restrict__ VbT)
{
    __shared__ float As[128 * 64];   // 128 rows x 256B, chunk-swizzled
    __shared__ short Bs[128 * 64];   // 128 rows x 128B, chunk-swizzled

    const float* A; const short* BT; const float* bias; short* out;
    int vmode, OUTROWS;
    if (blockIdx.y == 0)      { A = Aq; BT = WqT; bias = bq; out = Qb;  vmode = 0; OUTROWS = 1024; }
    else if (blockIdx.y == 1) { A = Ak; BT = WkT; bias = bk; out = Kb;  vmode = 0; OUTROWS = 1064; }
    else                      { A = Av; BT = WvT; bias = bv; out = VbT; vmode = 1; OUTROWS = 1064; }

    // XCD-grouped swizzle: id -> xcd x, m-panel mt = x + 8*(id>>5), n-tile (id>>3)&3
    const int id = blockIdx.x;
    const int mt = (id & 7) + 8 * (id >> 5);
    const int nt = (id >> 3) & 3;
    const int m0 = mt * 128, n0 = nt * 128;

    const int t = threadIdx.x;
    const int lane = t & 63, w = t >> 6;
    const int wr = w >> 1, wc = w & 1;
    const int l16 = lane & 15, g4 = lane >> 4;

    f32x4 acc[4][4];
#pragma unroll
    for (int i = 0; i < 4; ++i)
#pragma unroll
        for (int j = 0; j < 4; ++j) acc[i][j] = (f32x4){0.f, 0.f, 0.f, 0.f};

    const char* Asb = reinterpret_cast<const char*>(As);
    const char* Bsb = reinterpret_cast<const char*>(Bs);

    for (int kt = 0; kt < 8; ++kt) {
        const int k0 = kt * 64;
        // stage A (fp32): 8 passes, 16B/lane; LDS(row, ck) = G(row, ck ^ (row&7))
#pragma unroll
        for (int p = 0; p < 8; ++p) {
            const int row = p * 16 + (t >> 4);
            const int ck = (t & 15) ^ (row & 7);
            GL2LDS16(&A[(size_t)(m0 + row) * 512 + k0 + ck * 4],
                     (char*)As + (p * 256 + t) * 16);
        }
        // stage B (bf16): 4 passes
#pragma unroll
        for (int p = 0; p < 4; ++p) {
            const int row = p * 32 + (t >> 3);
            const int ck = (t & 7) ^ (row & 7);
            GL2LDS16(&BT[(size_t)(n0 + row) * 512 + k0 + ck * 8],
                     (char*)Bs + (p * 256 + t) * 16);
        }
        __syncthreads();
#pragma unroll
        for (int kk = 0; kk < 2; ++kk) {
            bf16x8 af[4], bfr[4];
#pragma unroll
            for (int mi = 0; mi < 4; ++mi) {
                const int row = wr * 64 + mi * 16 + l16;
                const int c0 = (kk * 8 + g4 * 2) ^ (row & 7);
                const int c1 = (kk * 8 + g4 * 2 + 1) ^ (row & 7);
                const float4 f0 = *reinterpret_cast<const float4*>(Asb + row * 256 + c0 * 16);
                const float4 f1 = *reinterpret_cast<const float4*>(Asb + row * 256 + c1 * 16);
                bf16x8 a;
                a[0] = f2bf(f0.x); a[1] = f2bf(f0.y); a[2] = f2bf(f0.z); a[3] = f2bf(f0.w);
                a[4] = f2bf(f1.x); a[5] = f2bf(f1.y); a[6] = f2bf(f1.z); a[7] = f2bf(f1.w);
                af[mi] = a;
            }
#pragma unroll
            for (int ni = 0; ni < 4; ++ni) {
                const int row = wc * 64 + ni * 16 + l16;
                const int ck = (kk * 4 + g4) ^ (row & 7);
                bfr[ni] = *reinterpret_cast<const bf16x8*>(Bsb + row * 128 + ck * 16);
            }
            __builtin_amdgcn_s_setprio(1);
#pragma unroll
            for (int mi = 0; mi < 4; ++mi)
#pragma unroll
                for (int ni = 0; ni < 4; ++ni)
                    acc[mi][ni] = __builtin_amdgcn_mfma_f32_16x16x32_bf16(af[mi], bfr[ni], acc[mi][ni], 0, 0, 0);
            __builtin_amdgcn_s_setprio(0);
        }
        __syncthreads();
    }
#pragma unroll
    for (int mi = 0; mi < 4; ++mi) {
#pragma unroll
        for (int ni = 0; ni < 4; ++ni) {
            const int col = n0 + wc * 64 + ni * 16 + l16;
            const int h = col >> 6, d = col & 63;
            const float bb = bias[col];
#pragma unroll
            for (int r = 0; r < 4; ++r) {
                const int rowg = m0 + wr * 64 + mi * 16 + g4 * 4 + r;
                const int b = rowg >> 10, nn = rowg & 1023;
                const short val = f2bf(acc[mi][ni][r] + bb);
                if (vmode)
                    out[(((size_t)b * 8 + h) * 64 + d) * 1088 + nn] = val;
                else
                    out[(((size_t)b * 8 + h) * OUTROWS + nn) * 64 + d] = val;
            }
        }
    }
}

// ---------------------------------------------------------------------------
// Flash attention: 2048 blocks (XCD-swizzled), 4 waves, 64 q-rows/block.
// KVBLK=64, 17 tiles.  aw modulates k<1024; mask k>=1064.  Defer-max (THR=8).
// ---------------------------------------------------------------------------
__global__ __launch_bounds__(256) void attn_kernel(
    const short* __restrict__ Qb, const short* __restrict__ Kb,
    const short* __restrict__ VbT, const float* __restrict__ aw,
    short* __restrict__ AO)
{
    __shared__ short Ks[64][72];
    __shared__ short Vs[64][72];       // [dv][k]
    __shared__ short Ps[4][16][72];    // wave-private P tiles [q][k]

    const int n = blockIdx.x;
    const int xcd = n & 7, s_ = n >> 3, j = s_ & 7, gh = s_ >> 3;
    const int g = gh * 8 + xcd;        // 0..255 = b*16+qt
    const int h = j, qt = g & 15, b = g >> 4;
    const int bh = b * 8 + h;
    const int t = threadIdx.x;
    const int lane = t & 63, w = t >> 6;
    const int l16 = lane & 15, g4 = lane >> 4;
    const int qrow0 = qt * 64 + w * 16;

    bf16x8 qf0, qf1;
    {
        const short* qp = Qb + ((size_t)bh * 1024 + qrow0 + l16) * 64 + g4 * 8;
        qf0 = *reinterpret_cast<const bf16x8*>(qp);
        qf1 = *reinterpret_cast<const bf16x8*>(qp + 32);
    }

    f32x4 O[4];
#pragma unroll
    for (int i = 0; i < 4; ++i) O[i] = (f32x4){0.f, 0.f, 0.f, 0.f};
    float m_r[4] = {-1e30f, -1e30f, -1e30f, -1e30f};
    float l_r[4] = {0.f, 0.f, 0.f, 0.f};

    const int str = t >> 2;            // staging row 0..63
    const int stc = (t & 3) * 16;      // 0,16,32,48 (shorts)

    for (int kt = 0; kt < 17; ++kt) {
        const int kb = kt * 64;
        const bool useaw = (kb < 1024);
        float awv[4][4];
        if (useaw) {
#pragma unroll
            for (int r = 0; r < 4; ++r) {
                const size_t awbase = ((size_t)b * 1024 + qrow0 + g4 * 4 + r) * 1024 + kb + l16;
#pragma unroll
                for (int sub = 0; sub < 4; ++sub)
                    awv[r][sub] = aw[awbase + sub * 16];
            }
        }
        {   // stage K tile [64][64]
            const int rg = kb + str;
            bf16x8 k0 = {0,0,0,0,0,0,0,0}, k1 = {0,0,0,0,0,0,0,0};
            if (rg < 1064) {
                const short* kp = &Kb[((size_t)bh * 1064 + rg) * 64 + stc];
                k0 = *reinterpret_cast<const bf16x8*>(kp);
                k1 = *reinterpret_cast<const bf16x8*>(kp + 8);
            }
            *reinterpret_cast<bf16x8*>(&Ks[str][stc]) = k0;
            *reinterpret_cast<bf16x8*>(&Ks[str][stc + 8]) = k1;
        }
        {   // stage V^T tile [64 dv][64 k] from VbT (vectorized)
            const short* vp = &VbT[((size_t)bh * 64 + str) * 1088 + kb + stc];
            bf16x8 v0 = {0,0,0,0,0,0,0,0}, v1 = {0,0,0,0,0,0,0,0};
            if (kb + stc + 8 <= 1064)  v0 = *reinterpret_cast<const bf16x8*>(vp);
            if (kb + stc + 16 <= 1064) v1 = *reinterpret_cast<const bf16x8*>(vp + 8);
            *reinterpret_cast<bf16x8*>(&Vs[str][stc]) = v0;
            *reinterpret_cast<bf16x8*>(&Vs[str][stc + 8]) = v1;
        }
        __syncthreads();

        // QK^T: S[sub] covers k = kb+sub*16+l16, q rows qrow0+g4*4+r
        f32x4 S[4];
        __builtin_amdgcn_s_setprio(1);
#pragma unroll
        for (int sub = 0; sub < 4; ++sub) {
            bf16x8 kf0 = *reinterpret_cast<const bf16x8*>(&Ks[sub * 16 + l16][g4 * 8]);
            bf16x8 kf1 = *reinterpret_cast<const bf16x8*>(&Ks[sub * 16 + l16][32 + g4 * 8]);
            f32x4 z = {0.f, 0.f, 0.f, 0.f};
            z = __builtin_amdgcn_mfma_f32_16x16x32_bf16(qf0, kf0, z, 0, 0, 0);
            S[sub] = __builtin_amdgcn_mfma_f32_16x16x32_bf16(qf1, kf1, z, 0, 0, 0);
        }
        __builtin_amdgcn_s_setprio(0);

        const bool tail = (kb + 64 > 1064);
        float sv[4][4], mx[4];
#pragma unroll
        for (int r = 0; r < 4; ++r) {
#pragma unroll
            for (int sub = 0; sub < 4; ++sub) {
                float x = S[sub][r] * 0.125f;
                if (useaw) x *= awv[r][sub];
                if (tail && (kb + sub * 16 + l16 >= 1064)) x = -1e30f;
                sv[r][sub] = x;
            }
            float m2 = fmaxf(fmaxf(sv[r][0], sv[r][1]), fmaxf(sv[r][2], sv[r][3]));
#pragma unroll
            for (int off = 1; off < 16; off <<= 1)
                m2 = fmaxf(m2, __shfl_xor(m2, off));
            mx[r] = m2;
        }
        // defer-max: only rescale when some row grew past threshold
        bool grew = false;
#pragma unroll
        for (int r = 0; r < 4; ++r) grew = grew || (mx[r] > m_r[r] + 8.0f);
        if (__any(grew)) {
#pragma unroll
            for (int r = 0; r < 4; ++r) {
                const float mn = fmaxf(m_r[r], mx[r]);
                const float corr = __expf(m_r[r] - mn);
                m_r[r] = mn;
                l_r[r] *= corr;
#pragma unroll
                for (int i = 0; i < 4; ++i) O[i][r] *= corr;
            }
        }
#pragma unroll
        for (int r = 0; r < 4; ++r) {
            float rs = 0.f;
#pragma unroll
            for (int sub = 0; sub < 4; ++sub) {
                const float p = __expf(sv[r][sub] - m_r[r]);
                rs += p;
                Ps[w][g4 * 4 + r][sub * 16 + l16] = f2bf(p);
            }
#pragma unroll
            for (int off = 1; off < 16; off <<= 1)
                rs += __shfl_xor(rs, off);
            l_r[r] += rs;
        }
        // PV
        bf16x8 pf0 = *reinterpret_cast<const bf16x8*>(&Ps[w][l16][g4 * 8]);
        bf16x8 pf1 = *reinterpret_cast<const bf16x8*>(&Ps[w][l16][32 + g4 * 8]);
        __builtin_amdgcn_s_setprio(1);
#pragma unroll
        for (int sub = 0; sub < 4; ++sub) {
            bf16x8 vf0 = *reinterpret_cast<const bf16x8*>(&Vs[sub * 16 + l16][g4 * 8]);
            bf16x8 vf1 = *reinterpret_cast<const bf16x8*>(&Vs[sub * 16 + l16][32 + g4 * 8]);
            O[sub] = __builtin_amdgcn_mfma_f32_16x16x32_bf16(pf0, vf0, O[sub], 0, 0, 0);
            O[sub] = __builtin_amdgcn_mfma_f32_16x16x32_bf16(pf1, vf1, O[sub], 0, 0, 0);
        }
        __builtin_amdgcn_s_setprio(0);
        __syncthreads();
    }
    // epilogue: normalize and store AO[b*1024+q][h*64+dv] bf16
#pragma unroll
    for (int r = 0; r < 4; ++r) {
        const float inv = 1.0f / l_r[r];
        const int qg = qrow0 + g4 * 4 + r;
        const size_t base = ((size_t)b * 1024 + qg) * 512 + h * 64;
#pragma unroll
        for (int sub = 0; sub < 4; ++sub)
            AO[base + sub * 16 + l16] = f2bf(O[sub][r] * inv);
    }
}

// ---------------------------------------------------------------------------
// Output GEMM v3 + bias + residual: out(fp32) = AO(bf16) @ WoT^T + bo + queries
// Same structure as proj v3 (both operands bf16).
// ---------------------------------------------------------------------------
__global__ __launch_bounds__(256) void out_gemm(
    const short* __restrict__ A, const short* __restrict__ BT,
    const float* __restrict__ bias, const float* __restrict__ resid,
    float* __restrict__ out)
{
    __shared__ short Asm[128 * 64];  // 128 rows x 128B, chunk-swizzled
    __shared__ short Bs[128 * 64];

    const int id = blockIdx.x;
    const int mt = (id & 7) + 8 * (id >> 5);
    const int nt = (id >> 3) & 3;
    const int m0 = mt * 128, n0 = nt * 128;

    const int t = threadIdx.x;
    const int lane = t & 63, w = t >> 6;
    const int wr = w >> 1, wc = w & 1;
    const int l16 = lane & 15, g4 = lane >> 4;

    f32x4 acc[4][4];
#pragma unroll
    for (int i = 0; i < 4; ++i)
#pragma unroll
        for (int j = 0; j < 4; ++j) acc[i][j] = (f32x4){0.f, 0.f, 0.f, 0.f};

    const char* Asb = reinterpret_cast<const char*>(Asm);
    const char* Bsb = reinterpret_cast<const char*>(Bs);

    for (int kt = 0; kt < 8; ++kt) {
        const int k0 = kt * 64;
#pragma unroll
        for (int p = 0; p < 4; ++p) {
            const int row = p * 32 + (t >> 3);
            const int ck = (t & 7) ^ (row & 7);
            GL2LDS16(&A[(size_t)(m0 + row) * 512 + k0 + ck * 8],
                     (char*)Asm + (p * 256 + t) * 16);
            GL2LDS16(&BT[(size_t)(n0 + row) * 512 + k0 + ck * 8],
                     (char*)Bs + (p * 256 + t) * 16);
        }
        __syncthreads();
#pragma unroll
        for (int kk = 0; kk < 2; ++kk) {
            bf16x8 af[4], bfr[4];
#pragma unroll
            for (int mi = 0; mi < 4; ++mi) {
                const int row = wr * 64 + mi * 16 + l16;
                const int ck = (kk * 4 + g4) ^ (row & 7);
                af[mi] = *reinterpret_cast<const bf16x8*>(Asb + row * 128 + ck * 16);
            }
#pragma unroll
            for (int ni = 0; ni < 4; ++ni) {
                const int row = wc * 64 + ni * 16 + l16;
                const int ck = (kk * 4 + g4) ^ (row & 7);
                bfr[ni] = *reinterpret_cast<const bf16x8*>(Bsb + row * 128 + ck * 16);
            }
            __builtin_amdgcn_s_setprio(1);
#pragma unroll
            for (int mi = 0; mi < 4; ++mi)
#pragma unroll
                for (int ni = 0; ni < 4; ++ni)
                    acc[mi][ni] = __builtin_amdgcn_mfma_f32_16x16x32_bf16(af[mi], bfr[ni], acc[mi][ni], 0, 0, 0);
            __builtin_amdgcn_s_setprio(0);
        }
        __syncthreads();
    }
#pragma unroll
    for (int mi = 0; mi < 4; ++mi) {
#pragma unroll
        for (int ni = 0; ni < 4; ++ni) {
            const int col = n0 + wc * 64 + ni * 16 + l16;
            const float bb = bias[col];
#pragma unroll
            for (int r = 0; r < 4; ++r) {
                const int rowg = m0 + wr * 64 + mi * 16 + g4 * 4 + r;
                out[(size_t)rowg * 512 + col] = acc[mi][ni][r] + bb + resid[(size_t)rowg * 512 + col];
            }
        }
    }
}

// ---------------------------------------------------------------------------
// LayerNorm in-place on d_out, one wave per 512-col row
// ---------------------------------------------------------------------------
__global__ __launch_bounds__(256) void ln_kernel(
    float* __restrict__ x, const float* __restrict__ gamma, const float* __restrict__ beta)
{
    const int row = blockIdx.x * 4 + (threadIdx.x >> 6);
    const int lane = threadIdx.x & 63;
    float* rp = x + (size_t)row * 512;
    const float4 v0 = *reinterpret_cast<const float4*>(&rp[lane * 4]);
    const float4 v1 = *reinterpret_cast<const float4*>(&rp[256 + lane * 4]);
    float s = v0.x + v0.y + v0.z + v0.w + v1.x + v1.y + v1.z + v1.w;
    float sq = v0.x * v0.x + v0.y * v0.y + v0.z * v0.z + v0.w * v0.w
             + v1.x * v1.x + v1.y * v1.y + v1.z * v1.z + v1.w * v1.w;
#pragma unroll
    for (int off = 1; off < 64; off <<= 1) {
        s += __shfl_xor(s, off);
        sq += __shfl_xor(sq, off);
    }
    const float mu = s * (1.f / 512.f);
    const float var = sq * (1.f / 512.f) - mu * mu;
    const float inv = rsqrtf(var + 1e-3f);
    const float4 g0 = *reinterpret_cast<const float4*>(&gamma[lane * 4]);
    const float4 g1 = *reinterpret_cast<const float4*>(&gamma[256 + lane * 4]);
    const float4 b0 = *reinterpret_cast<const float4*>(&beta[lane * 4]);
    const float4 b1 = *reinterpret_cast<const float4*>(&beta[256 + lane * 4]);
    float4 o0, o1;
    o0.x = (v0.x - mu) * inv * g0.x + b0.x;
    o0.y = (v0.y - mu) * inv * g0.y + b0.y;
    o0.z = (v0.z - mu) * inv * g0.z + b0.z;
    o0.w = (v0.w - mu) * inv * g0.w + b0.w;
    o1.x = (v1.x - mu) * inv * g1.x + b1.x;
    o1.y = (v1.y - mu) * inv * g1.y + b1.y;
    o1.z = (v1.z - mu) * inv * g1.z + b1.z;
    o1.w = (v1.w - mu) * inv * g1.w + b1.w;
    *reinterpret_cast<float4*>(&rp[lane * 4]) = o0;
    *reinterpret_cast<float4*>(&rp[256 + lane * 4]) = o1;
}

// ---------------------------------------------------------------------------
extern "C" void kernel_launch(void* const* d_in, const int* in_sizes, int n_in,
                              void* d_out, int out_size, void* d_ws, size_t ws_size,
                              hipStream_t stream) {
    const float* queries = (const float*)d_in[0];
    const float* keys    = (const float*)d_in[1];
    const float* values  = (const float*)d_in[2];
    const float* aw      = (const float*)d_in[3];
    const float* Wq = (const float*)d_in[4];
    const float* bq = (const float*)d_in[5];
    const float* Wk = (const float*)d_in[6];
    const float* bk = (const float*)d_in[7];
    const float* Wv = (const float*)d_in[8];
    const float* bv = (const float*)d_in[9];
    const float* Wo = (const float*)d_in[10];
    const float* bo = (const float*)d_in[11];
    const float* memK = (const float*)d_in[12];
    const float* memV = (const float*)d_in[13];
    const float* gamma = (const float*)d_in[14];
    const float* beta  = (const float*)d_in[15];
    float* out = (float*)d_out;

    char* ws = (char*)d_ws;
    short* WqT = (short*)(ws + 0);
    short* WkT = (short*)(ws + 524288);
    short* WvT = (short*)(ws + 1048576);
    short* WoT = (short*)(ws + 1572864);
    short* Qb  = (short*)(ws + 2097152);                       // 16.78 MB
    short* Kb  = (short*)(ws + 2097152 + 16777216);            // 17.43 MB
    short* VbT = (short*)(ws + 2097152 + 16777216 + 17432576); // 17.83 MB
    short* AO  = (short*)(ws + 2097152 + 16777216 + 17432576 + 17825792);

    wt_kernel<<<dim3(8, 8, 4), 256, 0, stream>>>(Wq, Wk, Wv, Wo, WqT, WkT, WvT, WoT);
    mem_kernel<<<dim3(1280), 256, 0, stream>>>(memK, memV, Kb, VbT);
    proj_gemm<<<dim3(512, 3), 256, 0, stream>>>(queries, keys, values,
                                                WqT, WkT, WvT, bq, bk, bv,
                                                Qb, Kb, VbT);
    attn_kernel<<<dim3(2048), 256, 0, stream>>>(Qb, Kb, VbT, aw, AO);
    out_gemm<<<dim3(512), 256, 0, stream>>>(AO, WoT, bo, queries, out);
    ln_kernel<<<dim3(4096), 256, 0, stream>>>(out, gamma, beta);
}